// Round 1
// baseline (84.047 us; speedup 1.0000x reference)
//
#include <hip/hip_runtime.h>
#include <math.h>

#define NQ 8
#define NDEPTH 3
#define FEAT 512
#define NCLS 10
#define NBATCH 8192

// ---------------------------------------------------------------------------
// R8: 2 batch elements per thread (ILP x2, 8192->4096 waves, one resident
// round), gate coefficients LDS->registers once shared by both elements,
// segmented encoding reduction, FWHT PauliZ readout, ds_swizzle gates.
// Gate application / CNOT-ladder math verbatim from the HW-verified R2 kernel.
// ---------------------------------------------------------------------------

// DPP helpers (HW-verified R2..R6)
template <int CTRL, int ROW_MASK>
__device__ __forceinline__ float dpp_term(float v) {
    return __int_as_float(__builtin_amdgcn_update_dpp(
        0, __float_as_int(v), CTRL, ROW_MASK, 0xf, true));
}

__device__ __forceinline__ float wave_sum_bcast(float v) {
    v += dpp_term<0x111, 0xf>(v); // row_shr:1
    v += dpp_term<0x112, 0xf>(v); // row_shr:2
    v += dpp_term<0x114, 0xf>(v); // row_shr:4
    v += dpp_term<0x118, 0xf>(v); // row_shr:8
    v += dpp_term<0x142, 0xa>(v); // row_bcast15
    v += dpp_term<0x143, 0xc>(v); // row_bcast31
    return __int_as_float(__builtin_amdgcn_readlane(__float_as_int(v), 63));
}

__device__ __forceinline__ float bcastlane(float v, int srclane) {
    return __int_as_float(__builtin_amdgcn_readlane(__float_as_int(v), srclane));
}

template <int CTRL>
__device__ __forceinline__ float dpp_xor(float v) {
    return __int_as_float(__builtin_amdgcn_update_dpp(
        0, __float_as_int(v), CTRL, 0xf, 0xf, true));
}

// ds_swizzle xor within 32-lane groups: pattern = (xor<<10)|0x1F
template <int PAT>
__device__ __forceinline__ float swz(float v) {
    return __int_as_float(__builtin_amdgcn_ds_swizzle(__float_as_int(v), PAT));
}

__device__ __forceinline__ float fast_tanh(float v) {
    float e = __expf(2.f * v);
    return 1.f - 2.f / (e + 1.f);
}

// ---- gate application on register-cached coefficients ----------------------
__device__ __forceinline__ void load_u(const float* g, float (&u)[8]) {
    float4 a = *(const float4*)g;
    float4 b = *(const float4*)(g + 4);
    u[0] = a.x; u[1] = a.y; u[2] = a.z; u[3] = a.w;
    u[4] = b.x; u[5] = b.y; u[6] = b.z; u[7] = b.w;
}

__device__ __forceinline__ void cgate_pair(const float (&u)[8],
        float& r0, float& i0, float& r1, float& i1) {
    float nr0 = u[0]*r0 - u[1]*i0 + u[2]*r1 - u[3]*i1;
    float ni0 = u[0]*i0 + u[1]*r0 + u[2]*i1 + u[3]*r1;
    float nr1 = u[4]*r0 - u[5]*i0 + u[6]*r1 - u[7]*i1;
    float ni1 = u[4]*i0 + u[5]*r0 + u[6]*i1 + u[7]*r1;
    r0 = nr0; i0 = ni0; r1 = nr1; i1 = ni1;
}

template <int PAT>
__device__ __forceinline__ void cgate_swz(const float (&u)[8], int bit,
        float (&re)[4], float (&im)[4]) {
    float dr  = bit ? u[6] : u[0], di = bit ? u[7] : u[1];
    float orr = bit ? u[4] : u[2], oi = bit ? u[5] : u[3];
#pragma unroll
    for (int j = 0; j < 4; j++) {
        float pr = swz<PAT>(re[j]);
        float pi = swz<PAT>(im[j]);
        float nr = dr*re[j] - di*im[j] + orr*pr - oi*pi;
        float ni = dr*im[j] + di*re[j] + orr*pi + oi*pr;
        re[j] = nr; im[j] = ni;
    }
}

__device__ __forceinline__ void cgate_shfl32(const float (&u)[8], int bit,
        float (&re)[4], float (&im)[4]) {
    float dr  = bit ? u[6] : u[0], di = bit ? u[7] : u[1];
    float orr = bit ? u[4] : u[2], oi = bit ? u[5] : u[3];
#pragma unroll
    for (int j = 0; j < 4; j++) {
        float pr = __shfl_xor(re[j], 32);
        float pi = __shfl_xor(im[j], 32);
        float nr = dr*re[j] - di*im[j] + orr*pr - oi*pi;
        float ni = dr*im[j] + di*re[j] + orr*pi + oi*pr;
        re[j] = nr; im[j] = ni;
    }
}

template <int CTRL>
__device__ __forceinline__ void cgate_dpp(const float (&u)[8], int bit,
        float (&re)[4], float (&im)[4]) {
    float dr  = bit ? u[6] : u[0], di = bit ? u[7] : u[1];
    float orr = bit ? u[4] : u[2], oi = bit ? u[5] : u[3];
#pragma unroll
    for (int j = 0; j < 4; j++) {
        float pr = dpp_xor<CTRL>(re[j]);
        float pi = dpp_xor<CTRL>(im[j]);
        float nr = dr*re[j] - di*im[j] + orr*pr - oi*pi;
        float ni = dr*im[j] + di*re[j] + orr*pi + oi*pr;
        re[j] = nr; im[j] = ni;
    }
}

// ---- segmented reduce: acc[8] per lane -> full sum of acc[lane>>3] ---------
// route q-bit2 via lane bit5, q-bit1 via bit4, q-bit0 via bit3; then reduce
// the remaining 8-lane group (bits 0..2).
__device__ __forceinline__ float seg_reduce8(const float (&a)[8], int lane) {
    bool h5 = (lane & 32) != 0, h4 = (lane & 16) != 0, h3 = (lane & 8) != 0;
    float r4[4];
#pragma unroll
    for (int k = 0; k < 4; k++) {
        float snd = h5 ? a[k] : a[4 + k];       // what partner keeps
        float rcv = __shfl_xor(snd, 32);
        float kp  = h5 ? a[4 + k] : a[k];       // what I keep
        r4[k] = kp + rcv;
    }
    float r2[2];
#pragma unroll
    for (int k = 0; k < 2; k++) {
        float snd = h4 ? r4[k] : r4[2 + k];
        float rcv = swz<0x401F>(snd);           // xor 16
        float kp  = h4 ? r4[2 + k] : r4[k];
        r2[k] = kp + rcv;
    }
    float snd = h3 ? r2[0] : r2[1];
    float rcv = swz<0x201F>(snd);               // xor 8
    float kp  = h3 ? r2[1] : r2[0];
    float r = kp + rcv;
    r += swz<0x101F>(r);                        // xor 4
    r += dpp_xor<0x4E>(r);                      // xor 2
    r += dpp_xor<0xB1>(r);                      // xor 1
    return r;
}

// ---- CNOT ladder (verbatim verified R2) ------------------------------------
__device__ __forceinline__ void cnot_ladder(int lane, int base, int base2,
        float (&re)[4], float (&im)[4]) {
    float t = re[1]; re[1] = re[3]; re[3] = t;
    t = im[1]; im[1] = im[3]; im[3] = t;
    re[0] = __shfl(re[0], base);  im[0] = __shfl(im[0], base);
    re[1] = __shfl(re[1], base);  im[1] = __shfl(im[1], base);
    re[2] = __shfl(re[2], base2); im[2] = __shfl(im[2], base2);
    re[3] = __shfl(re[3], base2); im[3] = __shfl(im[3], base2);
    int bit5 = (lane >> 5) & 1;
    float t0 = bit5 ? re[1] : re[0], t1 = bit5 ? re[0] : re[1];
    float t2 = bit5 ? re[3] : re[2], t3 = bit5 ? re[2] : re[3];
    re[0] = t0; re[1] = t1; re[2] = t2; re[3] = t3;
    t0 = bit5 ? im[1] : im[0]; t1 = bit5 ? im[0] : im[1];
    t2 = bit5 ? im[3] : im[2]; t3 = bit5 ? im[2] : im[3];
    im[0] = t0; im[1] = t1; im[2] = t2; im[3] = t3;
}

// ---- PauliZ readout: 2 wave-sums + 6-stage FWHT ----------------------------
__device__ __forceinline__ void readout(const float (&re)[4], const float (&im)[4],
        float sg1, float sg2, float sg4, float sg8, float sg16, float sg32,
        float (&eq)[8]) {
    float p0 = re[0]*re[0] + im[0]*im[0];
    float p1 = re[1]*re[1] + im[1]*im[1];
    float p2 = re[2]*re[2] + im[2]*im[2];
    float p3 = re[3]*re[3] + im[3]*im[3];
    float pt = p0 + p1 + p2 + p3;
    eq[0] = wave_sum_bcast(p0 - p1 + p2 - p3);
    eq[1] = wave_sum_bcast(p0 + p1 - p2 - p3);
    // FWHT over the 6 lane bits; stage: w' = partner + sign*w
    float w = pt;
    w = fmaf(sg1,  w, dpp_xor<0xB1>(w));
    w = fmaf(sg2,  w, dpp_xor<0x4E>(w));
    w = fmaf(sg4,  w, swz<0x101F>(w));
    w = fmaf(sg8,  w, swz<0x201F>(w));
    w = fmaf(sg16, w, swz<0x401F>(w));
    w = fmaf(sg32, w, __shfl_xor(w, 32));
    // lane m holds sum_l pt(l)*(-1)^popcount(m&l); single-bit masks = Z expvals
    eq[2] = bcastlane(w, 1);
    eq[3] = bcastlane(w, 2);
    eq[4] = bcastlane(w, 4);
    eq[5] = bcastlane(w, 8);
    eq[6] = bcastlane(w, 16);
    eq[7] = bcastlane(w, 32);
}

__global__ __launch_bounds__(256, 4) void qsim_kernel(
        const float* __restrict__ x, const float* __restrict__ proj_w,
        const float* __restrict__ qnn_w, const float* __restrict__ out_w,
        const float* __restrict__ out_b, float* __restrict__ out) {
    __shared__ float gl[NDEPTH * NQ * 8]; // fused RX*RY*RX per (layer,qubit)

    int tid = threadIdx.x;
    // ---- in-block gate table (verified precompute math; fast sincos: args
    // |t| <~ 0.03 rad so __sinf/__cosf abs err ~1e-7) ------------------------
    if (tid < NDEPTH * NQ) {
        float t0 = 0.5f * qnn_w[tid * 3 + 0];
        float t1 = 0.5f * qnn_w[tid * 3 + 1];
        float t2 = 0.5f * qnn_w[tid * 3 + 2];
        float c0 = __cosf(t0), s0 = __sinf(t0);
        float c1 = __cosf(t1), s1 = __sinf(t1);
        float c2 = __cosf(t2), s2 = __sinf(t2);
        // M1 = RY(t1)*RX(t0)
        float m00r =  c1 * c0, m00i =  s1 * s0;
        float m01r = -s1 * c0, m01i = -c1 * s0;
        float m10r =  s1 * c0, m10i = -c1 * s0;
        float m11r =  c1 * c0, m11i = -s1 * s0;
        // U = RX(t2)*M1
        float* g = gl + tid * 8;
        g[0] =  c2 * m00r + s2 * m10i;  g[1] =  c2 * m00i - s2 * m10r;
        g[2] =  c2 * m01r + s2 * m11i;  g[3] =  c2 * m01i - s2 * m11r;
        g[4] =  s2 * m00i + c2 * m10r;  g[5] = -s2 * m00r + c2 * m10i;
        g[6] =  s2 * m01i + c2 * m11r;  g[7] = -s2 * m01r + c2 * m11i;
    }
    __syncthreads();

    int lane = tid & 63;
    int wid  = tid >> 6;
    int b0 = blockIdx.x * 8 + wid * 2;
    int b1 = b0 + 1;

    // ---- encoding dots for BOTH elements; proj_w loads shared --------------
    const float4* xA = (const float4*)(x + (size_t)b0 * FEAT);
    const float4* xB = (const float4*)(x + (size_t)b1 * FEAT);
    float4 xa0 = xA[lane], xb0 = xA[lane + 64];
    float4 xa1 = xB[lane], xb1 = xB[lane + 64];
    float acc0[8], acc1[8];
#pragma unroll
    for (int q = 0; q < 8; q++) {
        const float4* pw4 = (const float4*)(proj_w + q * FEAT);
        float4 wa = pw4[lane], wb = pw4[lane + 64];
        acc0[q] = xa0.x*wa.x + xa0.y*wa.y + xa0.z*wa.z + xa0.w*wa.w
                + xb0.x*wb.x + xb0.y*wb.y + xb0.z*wb.z + xb0.w*wb.w;
        acc1[q] = xa1.x*wa.x + xa1.y*wa.y + xa1.z*wa.z + xa1.w*wa.w
                + xb1.x*wb.x + xb1.y*wb.y + xb1.z*wb.z + xb1.w*wb.w;
    }
    // segmented reduce: lane group g=lane>>3 ends with dq[g] fully summed
    float d0 = seg_reduce8(acc0, lane);
    float d1 = seg_reduce8(acc1, lane);
    float th0 = fast_tanh(d0) * 0.78539816339744830962f;
    float th1 = fast_tanh(d1) * 0.78539816339744830962f;
    float se0 = __sinf(th0), ce0 = __cosf(th0);
    float se1 = __sinf(th1), ce1 = __cosf(th1);
    float cq0[8], sq0[8], cq1[8], sq1[8];
#pragma unroll
    for (int q = 0; q < 8; q++) {
        cq0[q] = bcastlane(ce0, q * 8);
        sq0[q] = bcastlane(se0, q * 8);
        cq1[q] = bcastlane(ce1, q * 8);
        sq1[q] = bcastlane(se1, q * 8);
    }

    // ---- encoding layer as product state -----------------------------------
    float F0 = 1.f, F1 = 1.f;
#pragma unroll
    for (int q = 2; q < 8; q++) {
        int bit = (lane >> (q - 2)) & 1;
        F0 *= bit ? sq0[q] : cq0[q];
        F1 *= bit ? sq1[q] : cq1[q];
    }
    float re0[4], im0[4], re1[4], im1[4];
    re0[0] = F0 * cq0[0] * cq0[1];
    re0[1] = F0 * sq0[0] * cq0[1];
    re0[2] = F0 * cq0[0] * sq0[1];
    re0[3] = F0 * sq0[0] * sq0[1];
    re1[0] = F1 * cq1[0] * cq1[1];
    re1[1] = F1 * sq1[0] * cq1[1];
    re1[2] = F1 * cq1[0] * sq1[1];
    re1[3] = F1 * sq1[0] * sq1[1];
    im0[0] = im0[1] = im0[2] = im0[3] = 0.f;
    im1[0] = im1[1] = im1[2] = im1[3] = 0.f;

    // ---- variational layers: coefficients loaded once, applied to both -----
    int base  = lane ^ ((lane << 1) & 63);
    int base2 = base ^ 1;
#pragma unroll
    for (int l = 0; l < NDEPTH; l++) {
        const float* gb = gl + l * NQ * 8;
        float u[8];
        load_u(gb + 0, u);
        cgate_pair(u, re0[0], im0[0], re0[1], im0[1]);
        cgate_pair(u, re0[2], im0[2], re0[3], im0[3]);
        cgate_pair(u, re1[0], im1[0], re1[1], im1[1]);
        cgate_pair(u, re1[2], im1[2], re1[3], im1[3]);
        load_u(gb + 8, u);
        cgate_pair(u, re0[0], im0[0], re0[2], im0[2]);
        cgate_pair(u, re0[1], im0[1], re0[3], im0[3]);
        cgate_pair(u, re1[0], im1[0], re1[2], im1[2]);
        cgate_pair(u, re1[1], im1[1], re1[3], im1[3]);
        load_u(gb + 16, u);
        cgate_dpp<0xB1>(u, lane & 1, re0, im0);
        cgate_dpp<0xB1>(u, lane & 1, re1, im1);
        load_u(gb + 24, u);
        cgate_dpp<0x4E>(u, (lane >> 1) & 1, re0, im0);
        cgate_dpp<0x4E>(u, (lane >> 1) & 1, re1, im1);
        load_u(gb + 32, u);
        cgate_swz<0x101F>(u, (lane >> 2) & 1, re0, im0);
        cgate_swz<0x101F>(u, (lane >> 2) & 1, re1, im1);
        load_u(gb + 40, u);
        cgate_swz<0x201F>(u, (lane >> 3) & 1, re0, im0);
        cgate_swz<0x201F>(u, (lane >> 3) & 1, re1, im1);
        load_u(gb + 48, u);
        cgate_swz<0x401F>(u, (lane >> 4) & 1, re0, im0);
        cgate_swz<0x401F>(u, (lane >> 4) & 1, re1, im1);
        load_u(gb + 56, u);
        cgate_shfl32(u, (lane >> 5) & 1, re0, im0);
        cgate_shfl32(u, (lane >> 5) & 1, re1, im1);
        cnot_ladder(lane, base, base2, re0, im0);
        cnot_ladder(lane, base, base2, re1, im1);
    }

    // ---- PauliZ expectations ----------------------------------------------
    float sg1  = (lane & 1)  ? -1.f : 1.f;
    float sg2  = (lane & 2)  ? -1.f : 1.f;
    float sg4  = (lane & 4)  ? -1.f : 1.f;
    float sg8  = (lane & 8)  ? -1.f : 1.f;
    float sg16 = (lane & 16) ? -1.f : 1.f;
    float sg32 = (lane & 32) ? -1.f : 1.f;
    float eA[8], eB[8];
    readout(re0, im0, sg1, sg2, sg4, sg8, sg16, sg32, eA);
    readout(re1, im1, sg1, sg2, sg4, sg8, sg16, sg32, eB);

    // ---- output head: lanes 0..9 -> b0, lanes 32..41 -> b1 -----------------
    if (lane < NCLS) {
        const float* wrow = out_w + lane * NQ;
        float acc = out_b[lane];
#pragma unroll
        for (int q = 0; q < 8; q++) acc = fmaf(eA[q], wrow[q], acc);
        out[(size_t)b0 * NCLS + lane] = acc;
    } else if (lane >= 32 && lane < 32 + NCLS) {
        int c = lane - 32;
        const float* wrow = out_w + c * NQ;
        float acc = out_b[c];
#pragma unroll
        for (int q = 0; q < 8; q++) acc = fmaf(eB[q], wrow[q], acc);
        out[(size_t)b1 * NCLS + c] = acc;
    }
}

extern "C" void kernel_launch(void* const* d_in, const int* in_sizes, int n_in,
                              void* d_out, int out_size, void* d_ws, size_t ws_size,
                              hipStream_t stream) {
    const float* x      = (const float*)d_in[0];
    const float* proj_w = (const float*)d_in[1];
    const float* qnn_w  = (const float*)d_in[2];
    const float* out_w  = (const float*)d_in[3];
    const float* out_b  = (const float*)d_in[4];
    float* out = (float*)d_out;

    qsim_kernel<<<NBATCH / 8, 256, 0, stream>>>(x, proj_w, qnn_w, out_w, out_b, out);
}